// Round 6
// baseline (678.912 us; speedup 1.0000x reference)
//
#include <hip/hip_runtime.h>

typedef __attribute__((ext_vector_type(8))) short short8;
typedef __attribute__((ext_vector_type(4))) float floatx4;
typedef __attribute__((ext_vector_type(2))) float floatx2;

#define LOG2E 1.44269504088896340736f

// raw barrier: drains LDS only; x-staging global loads stay in flight
#define BAR() asm volatile("s_waitcnt lgkmcnt(0)\n\ts_barrier" ::: "memory")

__device__ __forceinline__ unsigned short f2bf(float f) {
  unsigned u = __float_as_uint(f);
  u += 0x7FFFu + ((u >> 16) & 1u);
  return (unsigned short)(u >> 16);
}

__device__ __forceinline__ unsigned cvtpk(float lo, float hi) {
  unsigned r;
  asm("v_cvt_pk_bf16_f32 %0, %1, %2" : "=v"(r) : "v"(lo), "v"(hi));
  return r;
}

__global__ __launch_bounds__(512, 4) void tlstm_kernel(
    const float* __restrict__ x, const float* __restrict__ tim,
    const float* __restrict__ Wi, const float* __restrict__ bi,
    const float* __restrict__ Wh, const float* __restrict__ bh,
    float* __restrict__ out)
{
  // state: 8 rows [h0,c0,h1,c1,h2,c2,h3,c3] x 256 cols bf16, double-buffered
  __shared__ __align__(16) unsigned short Sst[2 * 2048];   // 8 KB
  // x-tile: 8 rows (batch*2+parity) x 128 bf16, double-buffered
  __shared__ __align__(16) unsigned short Sx[2 * 1024];    // 4 KB
  __shared__ __align__(16) float WMt[1024];                // [t][4 batches]

  const int tid = threadIdx.x;
  const int wv  = tid >> 6;        // wave 0..7, owns cols [wv*32, wv*32+32)
  const int l   = tid & 63;
  const int q   = l >> 4;          // 0..3
  const int r   = l & 15;
  const int r8  = r & 7;           // duplicated A-row (lanes r and r+8 share)
  const int qt  = q >> 1;          // tile select: 0 -> cols +0..15, 1 -> +16..31
  const int q1  = q & 1;           // batch-pair select: batches 2*q1, 2*q1+1
  const int b0  = blockIdx.x * 4;  // 4 batches per block, 512 blocks

  const int col1 = wv * 32 + r;
  const int col2 = col1 + 16;
  const int wcol = wv * 32 + qt * 16 + r;  // the column this lane's procs own

  // ---- weights for BOTH 16-col tiles into registers (B-operand layout) ----
  short8 wh[2][8];
#pragma unroll
  for (int tx = 0; tx < 2; ++tx)
#pragma unroll
    for (int c = 0; c < 8; ++c)
#pragma unroll
      for (int j = 0; j < 8; ++j)
        wh[tx][c][j] = (short)f2bf(Wh[(c * 32 + q * 8 + j) * 256 + wv * 32 + tx * 16 + r]);
  short8 wi[2][4];
#pragma unroll
  for (int tx = 0; tx < 2; ++tx)
#pragma unroll
    for (int c = 0; c < 4; ++c)
#pragma unroll
      for (int j = 0; j < 8; ++j)
        wi[tx][c][j] = (short)f2bf(Wi[(c * 32 + q * 8 + j) * 256 + wv * 32 + tx * 16 + r]);
  const float bh1 = bh[col1], bh2 = bh[col2];
  const float bi1 = bi[col1], bi2 = bi[col2];

  // ---- loop-invariant swizzled addresses (ushort units) ----
  // frag read: addr(c) = r8*STRIDE + ((c*32+q*8) ^ (r8<<3)) = base + 32*(c^rbx)
  const int rbx = r8 >> 2;
  const int Bs  = r8 * 256 + ((q * 8) ^ ((r8 & 3) << 3));
  const int raE = Bs + 32 * rbx, raO = Bs + 32 * (1 - rbx);
  const int Bx  = r8 * 128 + ((q * 8) ^ ((r8 & 3) << 3));
  const int xaE = Bx + 32 * rbx, xaO = Bx + 32 * (1 - rbx);
  // state writes: rows 4q1..4q1+3 at col wcol, addr = R*256 + (wcol ^ (R<<3))
  const int R0 = 4 * q1;
  const int wr0 = R0 * 256       + (wcol ^ (R0 << 3));
  const int wr1 = (R0 + 1) * 256 + (wcol ^ ((R0 + 1) << 3));
  const int wr2 = (R0 + 2) * 256 + (wcol ^ ((R0 + 2) << 3));
  const int wr3 = (R0 + 3) * 256 + (wcol ^ ((R0 + 3) << 3));
  // x staging: wave w stages row w (batch w>>1, parity w&1), lane l -> 2 floats
  const int xwi = wv * 128 + ((2 * l) ^ (wv << 3));
  const float* xp = x + (long)(b0 + (wv >> 1)) * 32768 + (wv & 1) * 128 + l * 2;
  const int wm2 = 2 * q1;

  // ---- one-time init ----
  *(unsigned long long*)&Sst[tid * 4] = 0ULL;   // zero state buf0 (4 KB)
  for (int i = tid; i < 1020; i += 512) {
    int t = i >> 2, bl = i & 3;
    float t0 = tim[(b0 + bl) * 256 + t];
    float t1 = tim[(b0 + bl) * 256 + t + 1];
    WMt[i] = 1.f - 1.f / logf(t1 - t0 + 2.7193f);
  }
  {  // stage pair 0 into Sx buf0
    floatx2 v = *(const floatx2*)xp;
    *(unsigned*)&Sx[xwi] = cvtpk(v.x, v.y);
  }
  xp += 256;
  __syncthreads();

  float c0s = 0.f, c1s = 0.f, h0 = 0.f, h1 = 0.f, g0 = 0.f, g1 = 0.f;
  int xro = 0;    // x read buffer offset: 0 / 1024
  int wmi = 0;    // = 8*pair

  // gate math: 2x exp2 + 1x rcp per element (combined reciprocal)
  auto proc1 = [&](float z0, float cp0, float cin, float wmv,
                   float& cno, float& gno, float& hno, int ih, int ic, int woff) {
    float z  = fminf(fmaxf(z0,  -10.f), 10.f);
    float cp = fminf(fmaxf(cp0, -10.f), 10.f);
    float u  = __builtin_amdgcn_exp2f(-LOG2E * z);
    float u2 = u * u;
    float v  = __builtin_amdgcn_exp2f(-2.f * LOG2E * cp);
    float a1 = 1.f + u, a2 = 1.f + u2, a3 = 1.f + v;
    float p12 = a1 * a2;
    float D   = __builtin_amdgcn_rcpf(p12 * a3);
    float Da3 = D * a3;
    float g   = Da3 * a2;                        // sigmoid(z)
    float ir2 = Da3 * a1;                        // 1/(1+u2)
    float ir3 = D * p12;                         // 1/(1+v)
    float Cb  = fmaf(-u2, ir2, ir2);             // tanh(z)
    float Cs  = fmaf(-v, ir3, ir3);              // tanh(cp)
    float Cstar = fmaf(-Cs, wmv, cin);
    float cn = g * (Cstar + Cb);
    float s = Cb * Cb;                           // tanh(Cb) Taylor-13
    float P = fmaf(0.003592028f, s, -0.008863236f);
    P = fmaf(P, s, 0.021869488f);
    P = fmaf(P, s, -0.053968254f);
    P = fmaf(P, s, 0.133333333f);
    P = fmaf(P, s, -0.333333333f);
    P = fmaf(P, s, 1.0f);
    float hn = g * (Cb * P);
    Sst[woff + ih] = (unsigned short)((__float_as_uint(hn) + 0x8000u) >> 16);
    Sst[woff + ic] = (unsigned short)((__float_as_uint(cn) + 0x8000u) >> 16);
    cno = cn; gno = g; hno = hn;
  };

  auto dostep = [&](int roff, int woff, float xz0, float xz1, int wmoff) {
    short8 sf[8];
    sf[0] = *(const short8*)&Sst[roff + raE];
    sf[1] = *(const short8*)&Sst[roff + raO];
    sf[2] = *(const short8*)&Sst[roff + raE + 64];
    sf[3] = *(const short8*)&Sst[roff + raO + 64];
    sf[4] = *(const short8*)&Sst[roff + raE + 128];
    sf[5] = *(const short8*)&Sst[roff + raO + 128];
    sf[6] = *(const short8*)&Sst[roff + raE + 192];
    sf[7] = *(const short8*)&Sst[roff + raO + 192];
    floatx4 a1 = {bh1, bh1, bh1, bh1};
    floatx4 a2 = {bh2, bh2, bh2, bh2};
#pragma unroll
    for (int c = 0; c < 8; ++c) {
      a1 = __builtin_amdgcn_mfma_f32_16x16x32_bf16(sf[c], wh[0][c], a1, 0, 0, 0);
      a2 = __builtin_amdgcn_mfma_f32_16x16x32_bf16(sf[c], wh[1][c], a2, 0, 0, 0);
    }
    floatx2 wmv = *(const floatx2*)&WMt[wmoff + wm2];
    float z0  = (qt ? a2[0] : a1[0]) + xz0;
    float cp0 =  qt ? a2[1] : a1[1];
    float z1  = (qt ? a2[2] : a1[2]) + xz1;
    float cp1 =  qt ? a2[3] : a1[3];
    proc1(z0, cp0, c0s, wmv.x, c0s, g0, h0, wr0, wr1, woff);
    proc1(z1, cp1, c1s, wmv.y, c1s, g1, h1, wr2, wr3, woff);
    BAR();
  };

  float xz[4];  // tile-selected x-proj: [b2q1 tA, b2q1 tB, b2q1+1 tA, b2q1+1 tB]
  auto loadx = [&]() {
    short8 xf[4];
    xf[0] = *(const short8*)&Sx[xro + xaE];
    xf[1] = *(const short8*)&Sx[xro + xaO];
    xf[2] = *(const short8*)&Sx[xro + xaE + 64];
    xf[3] = *(const short8*)&Sx[xro + xaO + 64];
    floatx4 x1 = {bi1, bi1, bi1, bi1};
    floatx4 x2 = {bi2, bi2, bi2, bi2};
#pragma unroll
    for (int c = 0; c < 4; ++c) {
      x1 = __builtin_amdgcn_mfma_f32_16x16x32_bf16(xf[c], wi[0][c], x1, 0, 0, 0);
      x2 = __builtin_amdgcn_mfma_f32_16x16x32_bf16(xf[c], wi[1][c], x2, 0, 0, 0);
    }
    xz[0] = qt ? x2[0] : x1[0];
    xz[1] = qt ? x2[1] : x1[1];
    xz[2] = qt ? x2[2] : x1[2];
    xz[3] = qt ? x2[3] : x1[3];
  };

  for (int p = 0; p < 127; ++p) {
    floatx2 nv = *(const floatx2*)xp;   // next pair's x (hidden under step A)
    xp += 256;
    loadx();
    // step A (t even): read buf0, write buf1
    dostep(0, 2048, xz[0], xz[2], wmi);
    // finish staging next pair into the other x buffer
    *(unsigned*)&Sx[(xro ^ 1024) + xwi] = cvtpk(nv.x, nv.y);
    // step B (t odd): read buf1, write buf0
    dostep(2048, 0, xz[1], xz[3], wmi + 4);
    xro ^= 1024;
    wmi += 8;
  }

  // tail: t = 254 (step A of pair 127; staged at p=126)
  loadx();
  dostep(0, 2048, xz[0], xz[2], wmi);

  // ---- epilogue: res = g_last @ Wh + bh; g-tile overwrites buf1 ----
  Sst[2048 + wr0] = f2bf(g0);  Sst[2048 + wr1] = 0;
  Sst[2048 + wr2] = f2bf(g1);  Sst[2048 + wr3] = 0;
  BAR();
  short8 gf[8];
  gf[0] = *(const short8*)&Sst[2048 + raE];
  gf[1] = *(const short8*)&Sst[2048 + raO];
  gf[2] = *(const short8*)&Sst[2048 + raE + 64];
  gf[3] = *(const short8*)&Sst[2048 + raO + 64];
  gf[4] = *(const short8*)&Sst[2048 + raE + 128];
  gf[5] = *(const short8*)&Sst[2048 + raO + 128];
  gf[6] = *(const short8*)&Sst[2048 + raE + 192];
  gf[7] = *(const short8*)&Sst[2048 + raO + 192];
  floatx4 r1 = {bh1, bh1, bh1, bh1};
  floatx4 r2 = {bh2, bh2, bh2, bh2};
#pragma unroll
  for (int c = 0; c < 8; ++c) {
    r1 = __builtin_amdgcn_mfma_f32_16x16x32_bf16(gf[c], wh[0][c], r1, 0, 0, 0);
    r2 = __builtin_amdgcn_mfma_f32_16x16x32_bf16(gf[c], wh[1][c], r2, 0, 0, 0);
  }
  float res0 = qt ? r2[0] : r1[0];
  float res2 = qt ? r2[2] : r1[2];

  const long P  = 2048L * 256;
  const long o0 = (long)(b0 + 2 * q1) * 256;
  const long o1 = (long)(b0 + 2 * q1 + 1) * 256;
  out[o0 + wcol]         = res0;
  out[o1 + wcol]         = res2;
  out[P + o0 + wcol]     = h0;
  out[P + o1 + wcol]     = h1;
  out[2 * P + o0 + wcol] = c0s;
  out[2 * P + o1 + wcol] = c1s;
}

extern "C" void kernel_launch(void* const* d_in, const int* in_sizes, int n_in,
                              void* d_out, int out_size, void* d_ws, size_t ws_size,
                              hipStream_t stream) {
  const float* xin = (const float*)d_in[0];
  const float* tim = (const float*)d_in[1];
  const float* Wi  = (const float*)d_in[2];
  const float* bi  = (const float*)d_in[3];
  const float* Wh  = (const float*)d_in[4];
  const float* bh  = (const float*)d_in[5];
  tlstm_kernel<<<dim3(512), dim3(512), 0, stream>>>(xin, tim, Wi, bi, Wh, bh, (float*)d_out);
}

// Round 7
// 368.650 us; speedup vs baseline: 1.8416x; 1.8416x over previous
//
#include <hip/hip_runtime.h>

typedef __attribute__((ext_vector_type(8))) short short8;
typedef __attribute__((ext_vector_type(4))) float floatx4;
typedef __attribute__((ext_vector_type(2))) float floatx2;

#define LOG2E 1.44269504088896340736f

// raw barrier: drains LDS only; x-staging global loads stay in flight
#define BAR() asm volatile("s_waitcnt lgkmcnt(0)\n\ts_barrier" ::: "memory")

__device__ __forceinline__ unsigned short f2bf(float f) {
  unsigned u = __float_as_uint(f);
  u += 0x7FFFu + ((u >> 16) & 1u);
  return (unsigned short)(u >> 16);
}

__device__ __forceinline__ unsigned cvtpk(float lo, float hi) {
  unsigned r;
  asm("v_cvt_pk_bf16_f32 %0, %1, %2" : "=v"(r) : "v"(lo), "v"(hi));
  return r;
}

// NOTE on launch bounds (empirical, R4-R6): hipcc here treats the 2nd arg as
// CUDA-style min-blocks/CU. (512,4) -> 32 waves/CU -> 64-VGPR cap -> the 96
// VGPRs of register-resident weights spilled to scratch (R6: FETCH 1.44 GB,
// 679 us). (512,2) -> 16 waves/CU -> 128-VGPR cap: weights stay in registers.
__global__ __launch_bounds__(512, 2) void tlstm_kernel(
    const float* __restrict__ x, const float* __restrict__ tim,
    const float* __restrict__ Wi, const float* __restrict__ bi,
    const float* __restrict__ Wh, const float* __restrict__ bh,
    float* __restrict__ out)
{
  // state: 8 rows [h0,c0,h1,c1,h2,c2,h3,c3] x 256 cols bf16, double-buffered
  __shared__ __align__(16) unsigned short Sst[2 * 2048];   // 8 KB
  // x-tile: 8 rows (batch*2+parity) x 128 bf16, double-buffered
  __shared__ __align__(16) unsigned short Sx[2 * 1024];    // 4 KB
  __shared__ __align__(16) float WMt[1024];                // [t][4 batches]

  const int tid = threadIdx.x;
  const int wv  = tid >> 6;        // wave 0..7, owns cols [wv*32, wv*32+32)
  const int l   = tid & 63;
  const int q   = l >> 4;          // 0..3
  const int r   = l & 15;
  const int r8  = r & 7;           // duplicated A-row (lanes r and r+8 share)
  const int qt  = q >> 1;          // tile select: 0 -> cols +0..15, 1 -> +16..31
  const int q1  = q & 1;           // batch-pair select: batches 2*q1, 2*q1+1
  const int b0  = blockIdx.x * 4;  // 4 batches per block, 512 blocks

  const int col1 = wv * 32 + r;
  const int col2 = col1 + 16;
  const int wcol = wv * 32 + qt * 16 + r;  // the column this lane's procs own

  // ---- weights for BOTH 16-col tiles into registers (B-operand layout) ----
  short8 wh[2][8];
#pragma unroll
  for (int tx = 0; tx < 2; ++tx)
#pragma unroll
    for (int c = 0; c < 8; ++c)
#pragma unroll
      for (int j = 0; j < 8; ++j)
        wh[tx][c][j] = (short)f2bf(Wh[(c * 32 + q * 8 + j) * 256 + wv * 32 + tx * 16 + r]);
  short8 wi[2][4];
#pragma unroll
  for (int tx = 0; tx < 2; ++tx)
#pragma unroll
    for (int c = 0; c < 4; ++c)
#pragma unroll
      for (int j = 0; j < 8; ++j)
        wi[tx][c][j] = (short)f2bf(Wi[(c * 32 + q * 8 + j) * 256 + wv * 32 + tx * 16 + r]);
  const float bh1 = bh[col1], bh2 = bh[col2];
  const float bi1 = bi[col1], bi2 = bi[col2];

  // ---- loop-invariant swizzled addresses (ushort units) ----
  // frag read: addr(c) = r8*STRIDE + ((c*32+q*8) ^ (r8<<3)) = base + 32*(c^rbx)
  const int rbx = r8 >> 2;
  const int Bs  = r8 * 256 + ((q * 8) ^ ((r8 & 3) << 3));
  const int raE = Bs + 32 * rbx, raO = Bs + 32 * (1 - rbx);
  const int Bx  = r8 * 128 + ((q * 8) ^ ((r8 & 3) << 3));
  const int xaE = Bx + 32 * rbx, xaO = Bx + 32 * (1 - rbx);
  // state writes: rows 4q1..4q1+3 at col wcol, addr = R*256 + (wcol ^ (R<<3))
  const int R0 = 4 * q1;
  const int wr0 = R0 * 256       + (wcol ^ (R0 << 3));
  const int wr1 = (R0 + 1) * 256 + (wcol ^ ((R0 + 1) << 3));
  const int wr2 = (R0 + 2) * 256 + (wcol ^ ((R0 + 2) << 3));
  const int wr3 = (R0 + 3) * 256 + (wcol ^ ((R0 + 3) << 3));
  // x staging: wave w stages row w (batch w>>1, parity w&1), lane l -> 2 floats
  const int xwi = wv * 128 + ((2 * l) ^ (wv << 3));
  const float* xp = x + (long)(b0 + (wv >> 1)) * 32768 + (wv & 1) * 128 + l * 2;
  const int wm2 = 2 * q1;

  // ---- one-time init ----
  *(unsigned long long*)&Sst[tid * 4] = 0ULL;   // zero state buf0 (4 KB)
  for (int i = tid; i < 1020; i += 512) {
    int t = i >> 2, bl = i & 3;
    float t0 = tim[(b0 + bl) * 256 + t];
    float t1 = tim[(b0 + bl) * 256 + t + 1];
    WMt[i] = 1.f - 1.f / logf(t1 - t0 + 2.7193f);
  }
  {  // stage pair 0 into Sx buf0
    floatx2 v = *(const floatx2*)xp;
    *(unsigned*)&Sx[xwi] = cvtpk(v.x, v.y);
  }
  xp += 256;
  __syncthreads();

  float c0s = 0.f, c1s = 0.f, h0 = 0.f, h1 = 0.f, g0 = 0.f, g1 = 0.f;
  int xro = 0;    // x read buffer offset: 0 / 1024
  int wmi = 0;    // = 8*pair

  // gate math: 2x exp2 + 1x rcp per element (combined reciprocal)
  auto proc1 = [&](float z0, float cp0, float cin, float wmv,
                   float& cno, float& gno, float& hno, int ih, int ic, int woff) {
    float z  = fminf(fmaxf(z0,  -10.f), 10.f);
    float cp = fminf(fmaxf(cp0, -10.f), 10.f);
    float u  = __builtin_amdgcn_exp2f(-LOG2E * z);
    float u2 = u * u;
    float v  = __builtin_amdgcn_exp2f(-2.f * LOG2E * cp);
    float a1 = 1.f + u, a2 = 1.f + u2, a3 = 1.f + v;
    float p12 = a1 * a2;
    float D   = __builtin_amdgcn_rcpf(p12 * a3);
    float Da3 = D * a3;
    float g   = Da3 * a2;                        // sigmoid(z)
    float ir2 = Da3 * a1;                        // 1/(1+u2)
    float ir3 = D * p12;                         // 1/(1+v)
    float Cb  = fmaf(-u2, ir2, ir2);             // tanh(z)
    float Cs  = fmaf(-v, ir3, ir3);              // tanh(cp)
    float Cstar = fmaf(-Cs, wmv, cin);
    float cn = g * (Cstar + Cb);
    float s = Cb * Cb;                           // tanh(Cb) Taylor-13
    float P = fmaf(0.003592028f, s, -0.008863236f);
    P = fmaf(P, s, 0.021869488f);
    P = fmaf(P, s, -0.053968254f);
    P = fmaf(P, s, 0.133333333f);
    P = fmaf(P, s, -0.333333333f);
    P = fmaf(P, s, 1.0f);
    float hn = g * (Cb * P);
    Sst[woff + ih] = (unsigned short)((__float_as_uint(hn) + 0x8000u) >> 16);
    Sst[woff + ic] = (unsigned short)((__float_as_uint(cn) + 0x8000u) >> 16);
    cno = cn; gno = g; hno = hn;
  };

  auto dostep = [&](int roff, int woff, float xz0, float xz1, int wmoff) {
    short8 sf[8];
    sf[0] = *(const short8*)&Sst[roff + raE];
    sf[1] = *(const short8*)&Sst[roff + raO];
    sf[2] = *(const short8*)&Sst[roff + raE + 64];
    sf[3] = *(const short8*)&Sst[roff + raO + 64];
    sf[4] = *(const short8*)&Sst[roff + raE + 128];
    sf[5] = *(const short8*)&Sst[roff + raO + 128];
    sf[6] = *(const short8*)&Sst[roff + raE + 192];
    sf[7] = *(const short8*)&Sst[roff + raO + 192];
    floatx4 a1 = {bh1, bh1, bh1, bh1};
    floatx4 a2 = {bh2, bh2, bh2, bh2};
#pragma unroll
    for (int c = 0; c < 8; ++c) {
      a1 = __builtin_amdgcn_mfma_f32_16x16x32_bf16(sf[c], wh[0][c], a1, 0, 0, 0);
      a2 = __builtin_amdgcn_mfma_f32_16x16x32_bf16(sf[c], wh[1][c], a2, 0, 0, 0);
    }
    floatx2 wmv = *(const floatx2*)&WMt[wmoff + wm2];
    float z0  = (qt ? a2[0] : a1[0]) + xz0;
    float cp0 =  qt ? a2[1] : a1[1];
    float z1  = (qt ? a2[2] : a1[2]) + xz1;
    float cp1 =  qt ? a2[3] : a1[3];
    proc1(z0, cp0, c0s, wmv.x, c0s, g0, h0, wr0, wr1, woff);
    proc1(z1, cp1, c1s, wmv.y, c1s, g1, h1, wr2, wr3, woff);
    BAR();
  };

  float xz[4];  // tile-selected x-proj: [b2q1 tA, b2q1 tB, b2q1+1 tA, b2q1+1 tB]
  auto loadx = [&]() {
    short8 xf[4];
    xf[0] = *(const short8*)&Sx[xro + xaE];
    xf[1] = *(const short8*)&Sx[xro + xaO];
    xf[2] = *(const short8*)&Sx[xro + xaE + 64];
    xf[3] = *(const short8*)&Sx[xro + xaO + 64];
    floatx4 x1 = {bi1, bi1, bi1, bi1};
    floatx4 x2 = {bi2, bi2, bi2, bi2};
#pragma unroll
    for (int c = 0; c < 4; ++c) {
      x1 = __builtin_amdgcn_mfma_f32_16x16x32_bf16(xf[c], wi[0][c], x1, 0, 0, 0);
      x2 = __builtin_amdgcn_mfma_f32_16x16x32_bf16(xf[c], wi[1][c], x2, 0, 0, 0);
    }
    xz[0] = qt ? x2[0] : x1[0];
    xz[1] = qt ? x2[1] : x1[1];
    xz[2] = qt ? x2[2] : x1[2];
    xz[3] = qt ? x2[3] : x1[3];
  };

  for (int p = 0; p < 127; ++p) {
    floatx2 nv = *(const floatx2*)xp;   // next pair's x (hidden under step A)
    xp += 256;
    loadx();
    // step A (t even): read buf0, write buf1
    dostep(0, 2048, xz[0], xz[2], wmi);
    // finish staging next pair into the other x buffer
    *(unsigned*)&Sx[(xro ^ 1024) + xwi] = cvtpk(nv.x, nv.y);
    // step B (t odd): read buf1, write buf0
    dostep(2048, 0, xz[1], xz[3], wmi + 4);
    xro ^= 1024;
    wmi += 8;
  }

  // tail: t = 254 (step A of pair 127; staged at p=126)
  loadx();
  dostep(0, 2048, xz[0], xz[2], wmi);

  // ---- epilogue: res = g_last @ Wh + bh; g-tile overwrites buf1 ----
  Sst[2048 + wr0] = f2bf(g0);  Sst[2048 + wr1] = 0;
  Sst[2048 + wr2] = f2bf(g1);  Sst[2048 + wr3] = 0;
  BAR();
  short8 gf[8];
  gf[0] = *(const short8*)&Sst[2048 + raE];
  gf[1] = *(const short8*)&Sst[2048 + raO];
  gf[2] = *(const short8*)&Sst[2048 + raE + 64];
  gf[3] = *(const short8*)&Sst[2048 + raO + 64];
  gf[4] = *(const short8*)&Sst[2048 + raE + 128];
  gf[5] = *(const short8*)&Sst[2048 + raO + 128];
  gf[6] = *(const short8*)&Sst[2048 + raE + 192];
  gf[7] = *(const short8*)&Sst[2048 + raO + 192];
  floatx4 r1 = {bh1, bh1, bh1, bh1};
  floatx4 r2 = {bh2, bh2, bh2, bh2};
#pragma unroll
  for (int c = 0; c < 8; ++c) {
    r1 = __builtin_amdgcn_mfma_f32_16x16x32_bf16(gf[c], wh[0][c], r1, 0, 0, 0);
    r2 = __builtin_amdgcn_mfma_f32_16x16x32_bf16(gf[c], wh[1][c], r2, 0, 0, 0);
  }
  float res0 = qt ? r2[0] : r1[0];
  float res2 = qt ? r2[2] : r1[2];

  const long P  = 2048L * 256;
  const long o0 = (long)(b0 + 2 * q1) * 256;
  const long o1 = (long)(b0 + 2 * q1 + 1) * 256;
  out[o0 + wcol]         = res0;
  out[o1 + wcol]         = res2;
  out[P + o0 + wcol]     = h0;
  out[P + o1 + wcol]     = h1;
  out[2 * P + o0 + wcol] = c0s;
  out[2 * P + o1 + wcol] = c1s;
}

extern "C" void kernel_launch(void* const* d_in, const int* in_sizes, int n_in,
                              void* d_out, int out_size, void* d_ws, size_t ws_size,
                              hipStream_t stream) {
  const float* xin = (const float*)d_in[0];
  const float* tim = (const float*)d_in[1];
  const float* Wi  = (const float*)d_in[2];
  const float* bi  = (const float*)d_in[3];
  const float* Wh  = (const float*)d_in[4];
  const float* bh  = (const float*)d_in[5];
  tlstm_kernel<<<dim3(512), dim3(512), 0, stream>>>(xin, tim, Wi, bi, Wh, bh, (float*)d_out);
}

// Round 8
// 263.563 us; speedup vs baseline: 2.5759x; 1.3987x over previous
//
#include <hip/hip_runtime.h>

typedef __attribute__((ext_vector_type(8))) short short8;
typedef __attribute__((ext_vector_type(4))) float floatx4;
typedef __attribute__((ext_vector_type(2))) float floatx2;
typedef __attribute__((ext_vector_type(2))) unsigned uintx2;

#define LOG2E 1.44269504088896340736f

// raw barrier: drains LDS only; global loads stay in flight
#define BAR() asm volatile("s_waitcnt lgkmcnt(0)\n\ts_barrier" ::: "memory")

__device__ __forceinline__ unsigned short f2bf(float f) {
  unsigned u = __float_as_uint(f);
  u += 0x7FFFu + ((u >> 16) & 1u);
  return (unsigned short)(u >> 16);
}

__device__ __forceinline__ unsigned cvtpk(float lo, float hi) {
  unsigned r;
  asm("v_cvt_pk_bf16_f32 %0, %1, %2" : "=v"(r) : "v"(lo), "v"(hi));
  return r;
}

// Grid is 256 blocks -> exactly 1 block/CU. Take the 256-VGPR cap (512,1):
// the 96-VGPR register-resident weight set can never spill (R6 lesson).
__global__ __launch_bounds__(512, 1) void tlstm_kernel(
    const float* __restrict__ x, const float* __restrict__ tim,
    const float* __restrict__ Wi, const float* __restrict__ bi,
    const float* __restrict__ Wh, const float* __restrict__ bh,
    float* __restrict__ out)
{
  // state: 16 rows [h0,c0,...,h7,c7] x 256 k, row stride 264 (+8 pad), dbuf.
  // 528B row stride == 16 mod 512 -> bank quad = (r+q+4c) mod 8: even spread.
  __shared__ __align__(16) unsigned short Sst[2 * 4224];   // 16.5 KB
  // x-tile: 16 rows (2*batch+parity) x 128 k, stride 136, dbuf
  __shared__ __align__(16) unsigned short Sx[2 * 2176];    //  8.5 KB
  __shared__ __align__(16) float WMt[2048];                // [t][8 batches]

  const int tid = threadIdx.x;
  const int wv  = tid >> 6;        // wave 0..7, owns cols [wv*32, wv*32+32)
  const int l   = tid & 63;
  const int q   = l >> 4;          // k-group / D-row-group
  const int r   = l & 15;          // A-row / D-col
  const int b0  = blockIdx.x * 8;  // 8 batches per block, 256 blocks

  const int col1 = wv * 32 + r;
  const int col2 = col1 + 16;

  // ---- weights for both 16-col tiles into registers (B-operand layout) ----
  short8 wh[2][8];
#pragma unroll
  for (int tx = 0; tx < 2; ++tx)
#pragma unroll
    for (int c = 0; c < 8; ++c)
#pragma unroll
      for (int j = 0; j < 8; ++j)
        wh[tx][c][j] = (short)f2bf(Wh[(c * 32 + q * 8 + j) * 256 + wv * 32 + tx * 16 + r]);
  short8 wi[2][4];
#pragma unroll
  for (int tx = 0; tx < 2; ++tx)
#pragma unroll
    for (int c = 0; c < 4; ++c)
#pragma unroll
      for (int j = 0; j < 8; ++j)
        wi[tx][c][j] = (short)f2bf(Wi[(c * 32 + q * 8 + j) * 256 + wv * 32 + tx * 16 + r]);
  const float bh1 = bh[col1], bh2 = bh[col2];
  const float bi1 = bi[col1], bi2 = bi[col2];

  // ---- loop-invariant addresses (ushort units, plain padded layout) ----
  const int raS = r * 264 + q * 8;                   // + 32c (+buf offset)
  const int raX = r * 136 + q * 8;                   // + 32c (+buf offset)
  const int wrA = (4 * q) * 264 + col1;              // h-row of batch 2q @ col1
  // x staging: wave wv stages rows {2wv,2wv+1} = batch wv, both parities
  const int xw  = (2 * wv + (l >> 5)) * 136 + 4 * (l & 31);
  const float* xbase = x + (long)(b0 + wv) * 32768 + (l >> 5) * 128 + 4 * (l & 31);

  // ---- one-time init ----
  {
    unsigned* S32 = (unsigned*)Sst;
    for (int i = tid; i < 2112; i += 512) S32[i] = 0;    // zero state buf0
  }
  for (int i = tid; i < 2040; i += 512) {
    int t = i >> 3, bl = i & 7;
    float t0 = tim[(b0 + bl) * 256 + t];
    float t1 = tim[(b0 + bl) * 256 + t + 1];
    WMt[i] = 1.f - 1.f / logf(t1 - t0 + 2.7193f);
  }
  {  // stage pair 0 into Sx buf0
    floatx4 v = *(const floatx4*)xbase;
    uintx2 pk = {cvtpk(v.x, v.y), cvtpk(v.z, v.w)};
    *(uintx2*)&Sx[xw] = pk;
  }
  __syncthreads();

  // lane-resident state for its 4 (batch,col) outputs
  float cT1B0 = 0.f, cT1B1 = 0.f, cT2B0 = 0.f, cT2B1 = 0.f;
  float hT1B0 = 0.f, hT1B1 = 0.f, hT2B0 = 0.f, hT2B1 = 0.f;
  float gT1B0 = 0.f, gT1B1 = 0.f, gT2B0 = 0.f, gT2B1 = 0.f;
  int xro = 0;  // Sx read buffer offset: 0 / 2176

  // gate math: 2x exp2 + 1x rcp per element (combined reciprocal)
  auto proc1 = [&](float z0, float cp0, float cin, float wmv,
                   float& cno, float& gno, float& hno, int ih, int woff) {
    float z  = fminf(fmaxf(z0,  -10.f), 10.f);
    float cp = fminf(fmaxf(cp0, -10.f), 10.f);
    float u  = __builtin_amdgcn_exp2f(-LOG2E * z);
    float u2 = u * u;
    float v  = __builtin_amdgcn_exp2f(-2.f * LOG2E * cp);
    float a1 = 1.f + u, a2 = 1.f + u2, a3 = 1.f + v;
    float p12 = a1 * a2;
    float D   = __builtin_amdgcn_rcpf(p12 * a3);
    float Da3 = D * a3;
    float g   = Da3 * a2;                        // sigmoid(z)
    float ir2 = Da3 * a1;                        // 1/(1+u2)
    float ir3 = D * p12;                         // 1/(1+v)
    float Cb  = fmaf(-u2, ir2, ir2);             // tanh(z)
    float Cs  = fmaf(-v, ir3, ir3);              // tanh(cp)
    float Cstar = fmaf(-Cs, wmv, cin);
    float cn = g * (Cstar + Cb);
    float s = Cb * Cb;                           // tanh(Cb) Taylor-13
    float P = fmaf(0.003592028f, s, -0.008863236f);
    P = fmaf(P, s, 0.021869488f);
    P = fmaf(P, s, -0.053968254f);
    P = fmaf(P, s, 0.133333333f);
    P = fmaf(P, s, -0.333333333f);
    P = fmaf(P, s, 1.0f);
    float hn = g * (Cb * P);
    Sst[woff + ih]       = (unsigned short)((__float_as_uint(hn) + 0x8000u) >> 16);
    Sst[woff + ih + 264] = (unsigned short)((__float_as_uint(cn) + 0x8000u) >> 16);
    cno = cn; gno = g; hno = hn;
  };

  floatx4 xa1, xa2;  // x-proj (+bi): [b2q parA, b2q parB, b2q+1 parA, b2q+1 parB]
  auto loadx = [&]() {
    short8 xf[4];
#pragma unroll
    for (int c = 0; c < 4; ++c)
      xf[c] = *(const short8*)&Sx[xro + raX + 32 * c];
    floatx4 x1 = {bi1, bi1, bi1, bi1};
    floatx4 x2 = {bi2, bi2, bi2, bi2};
#pragma unroll
    for (int c = 0; c < 4; ++c) {
      x1 = __builtin_amdgcn_mfma_f32_16x16x32_bf16(xf[c], wi[0][c], x1, 0, 0, 0);
      x2 = __builtin_amdgcn_mfma_f32_16x16x32_bf16(xf[c], wi[1][c], x2, 0, 0, 0);
    }
    xa1 = x1; xa2 = x2;
  };

  auto dostep = [&](int roff, int woff, int par, int wmoff) {
    short8 sf[8];
#pragma unroll
    for (int c = 0; c < 8; ++c)
      sf[c] = *(const short8*)&Sst[roff + raS + 32 * c];
    floatx4 a1 = {bh1, bh1, bh1, bh1};
    floatx4 a2 = {bh2, bh2, bh2, bh2};
#pragma unroll
    for (int c = 0; c < 8; ++c) {
      a1 = __builtin_amdgcn_mfma_f32_16x16x32_bf16(sf[c], wh[0][c], a1, 0, 0, 0);
      a2 = __builtin_amdgcn_mfma_f32_16x16x32_bf16(sf[c], wh[1][c], a2, 0, 0, 0);
    }
    floatx2 wm = *(const floatx2*)&WMt[wmoff];
    proc1(a1[0] + xa1[par],     a1[1], cT1B0, wm.x, cT1B0, gT1B0, hT1B0, wrA,        woff);
    proc1(a1[2] + xa1[2 + par], a1[3], cT1B1, wm.y, cT1B1, gT1B1, hT1B1, wrA + 528,  woff);
    proc1(a2[0] + xa2[par],     a2[1], cT2B0, wm.x, cT2B0, gT2B0, hT2B0, wrA + 16,   woff);
    proc1(a2[2] + xa2[2 + par], a2[3], cT2B1, wm.y, cT2B1, gT2B1, hT2B1, wrA + 544,  woff);
    BAR();
  };

  for (int p = 0; p < 127; ++p) {
    floatx4 nv = *(const floatx4*)(xbase + (p + 1) * 256);  // next pair's x
    loadx();
    // step A (t = 2p): read buf0, write buf1
    dostep(0, 4224, 0, 16 * p + 2 * q);
    {  // finish staging next pair into the other x buffer
      uintx2 pk = {cvtpk(nv.x, nv.y), cvtpk(nv.z, nv.w)};
      *(uintx2*)&Sx[(xro ^ 2176) + xw] = pk;
    }
    // step B (t = 2p+1): read buf1, write buf0
    dostep(4224, 0, 1, 16 * p + 8 + 2 * q);
    xro ^= 2176;
  }

  // tail: t = 254 (step A of pair 127; staged at p=126)
  loadx();
  dostep(0, 4224, 0, 16 * 127 + 2 * q);

  // ---- epilogue: res = g_last @ Wh + bh; g-tile into buf0 ----
  Sst[wrA]       = f2bf(gT1B0);  Sst[wrA + 264] = 0;
  Sst[wrA + 528] = f2bf(gT1B1);  Sst[wrA + 792] = 0;
  Sst[wrA + 16]  = f2bf(gT2B0);  Sst[wrA + 280] = 0;
  Sst[wrA + 544] = f2bf(gT2B1);  Sst[wrA + 808] = 0;
  BAR();
  short8 gf[8];
#pragma unroll
  for (int c = 0; c < 8; ++c)
    gf[c] = *(const short8*)&Sst[raS + 32 * c];
  floatx4 r1 = {bh1, bh1, bh1, bh1};
  floatx4 r2 = {bh2, bh2, bh2, bh2};
#pragma unroll
  for (int c = 0; c < 8; ++c) {
    r1 = __builtin_amdgcn_mfma_f32_16x16x32_bf16(gf[c], wh[0][c], r1, 0, 0, 0);
    r2 = __builtin_amdgcn_mfma_f32_16x16x32_bf16(gf[c], wh[1][c], r2, 0, 0, 0);
  }

  const long P  = 2048L * 256;
  const long o0 = (long)(b0 + 2 * q) * 256;
  const long o1 = (long)(b0 + 2 * q + 1) * 256;
  out[o0 + col1]         = r1[0];
  out[o1 + col1]         = r1[2];
  out[o0 + col2]         = r2[0];
  out[o1 + col2]         = r2[2];
  out[P + o0 + col1]     = hT1B0;
  out[P + o1 + col1]     = hT1B1;
  out[P + o0 + col2]     = hT2B0;
  out[P + o1 + col2]     = hT2B1;
  out[2 * P + o0 + col1] = cT1B0;
  out[2 * P + o1 + col1] = cT1B1;
  out[2 * P + o0 + col2] = cT2B0;
  out[2 * P + o1 + col2] = cT2B1;
}

extern "C" void kernel_launch(void* const* d_in, const int* in_sizes, int n_in,
                              void* d_out, int out_size, void* d_ws, size_t ws_size,
                              hipStream_t stream) {
  const float* xin = (const float*)d_in[0];
  const float* tim = (const float*)d_in[1];
  const float* Wi  = (const float*)d_in[2];
  const float* bi  = (const float*)d_in[3];
  const float* Wh  = (const float*)d_in[4];
  const float* bh  = (const float*)d_in[5];
  tlstm_kernel<<<dim3(256), dim3(512), 0, stream>>>(xin, tim, Wi, bi, Wh, bh, (float*)d_out);
}

// Round 9
// 254.296 us; speedup vs baseline: 2.6698x; 1.0364x over previous
//
#include <hip/hip_runtime.h>

typedef __attribute__((ext_vector_type(8))) short short8;
typedef __attribute__((ext_vector_type(4))) float floatx4;
typedef __attribute__((ext_vector_type(2))) float floatx2;
typedef __attribute__((ext_vector_type(2))) unsigned uintx2;

#define LOG2E 1.44269504088896340736f

// raw barrier: drains LDS only; global loads stay in flight
#define BAR() asm volatile("s_waitcnt lgkmcnt(0)\n\ts_barrier" ::: "memory")

__device__ __forceinline__ floatx2 F2(float v) { return (floatx2){v, v}; }

__device__ __forceinline__ unsigned short f2bf(float f) {
  unsigned u = __float_as_uint(f);
  u += 0x7FFFu + ((u >> 16) & 1u);
  return (unsigned short)(u >> 16);
}

__device__ __forceinline__ unsigned cvtpk(float lo, float hi) {
  unsigned r;
  asm("v_cvt_pk_bf16_f32 %0, %1, %2" : "=v"(r) : "v"(lo), "v"(hi));
  return r;
}

// 1 block/CU (grid=256): take the 256-VGPR cap; weights can never spill (R6).
__global__ __launch_bounds__(512, 1) void tlstm_kernel(
    const float* __restrict__ x, const float* __restrict__ tim,
    const float* __restrict__ Wi, const float* __restrict__ bi,
    const float* __restrict__ Wh, const float* __restrict__ bh,
    float* __restrict__ out)
{
  // state: 16 rows [h0,c0,...,h7,c7] x 256 k, row stride 264 (+8 pad), dbuf.
  // 528B row stride == 16 mod 512 -> bank quad = (r+q+4c) mod 8: even spread.
  __shared__ __align__(16) unsigned short Sst[2 * 4224];   // 16.5 KB
  __shared__ __align__(16) unsigned short Sx[2 * 2176];    //  8.5 KB
  __shared__ __align__(16) float WMt[2048];                // [t][8 batches]

  const int tid = threadIdx.x;
  const int wv  = tid >> 6;        // wave 0..7, owns cols [wv*32, wv*32+32)
  const int l   = tid & 63;
  const int q   = l >> 4;          // k-group / D-row-group
  const int r   = l & 15;          // A-row / D-col
  const int b0  = blockIdx.x * 8;  // 8 batches per block, 256 blocks

  const int col1 = wv * 32 + r;
  const int col2 = col1 + 16;

  // ---- weights for both 16-col tiles into registers (B-operand layout) ----
  short8 wh[2][8];
#pragma unroll
  for (int tx = 0; tx < 2; ++tx)
#pragma unroll
    for (int c = 0; c < 8; ++c)
#pragma unroll
      for (int j = 0; j < 8; ++j)
        wh[tx][c][j] = (short)f2bf(Wh[(c * 32 + q * 8 + j) * 256 + wv * 32 + tx * 16 + r]);
  short8 wi[2][4];
#pragma unroll
  for (int tx = 0; tx < 2; ++tx)
#pragma unroll
    for (int c = 0; c < 4; ++c)
#pragma unroll
      for (int j = 0; j < 8; ++j)
        wi[tx][c][j] = (short)f2bf(Wi[(c * 32 + q * 8 + j) * 256 + wv * 32 + tx * 16 + r]);
  const float bh1 = bh[col1], bh2 = bh[col2];
  const float bi1 = bi[col1], bi2 = bi[col2];

  // ---- loop-invariant addresses (ushort units) ----
  const int raS = r * 264 + q * 8;
  const int raX = r * 136 + q * 8;
  const int wrA = (4 * q) * 264 + col1;
  const int xw  = (2 * wv + (l >> 5)) * 136 + 4 * (l & 31);
  const float* xbase = x + (long)(b0 + wv) * 32768 + (l >> 5) * 128 + 4 * (l & 31);

  // ---- one-time init ----
  {
    unsigned* S32 = (unsigned*)Sst;
    for (int i = tid; i < 2112; i += 512) S32[i] = 0;
  }
  for (int i = tid; i < 2040; i += 512) {
    int t = i >> 3, bl = i & 7;
    float t0 = tim[(b0 + bl) * 256 + t];
    float t1 = tim[(b0 + bl) * 256 + t + 1];
    WMt[i] = 1.f - 1.f / logf(t1 - t0 + 2.7193f);
  }
  {
    floatx4 v = *(const floatx4*)xbase;
    uintx2 pk = {cvtpk(v.x, v.y), cvtpk(v.z, v.w)};
    *(uintx2*)&Sx[xw] = pk;
  }
  __syncthreads();

  // lane state as (col1,col2) pairs: P0 = batch 2q, P1 = batch 2q+1
  floatx2 cP0 = F2(0.f), cP1 = F2(0.f);
  floatx2 hP0 = F2(0.f), hP1 = F2(0.f);
  floatx2 gP0 = F2(0.f), gP1 = F2(0.f);
  int xro = 0;

  // packed gate math: pairs processed via v_pk_* fp32; 6 trans per pair
  auto proc2 = [&](floatx2 zin, floatx2 cpin, floatx2& cio, floatx2& gio,
                   floatx2& hio, float wmv, int ih0, int ih1, int woff) {
    floatx2 z  = __builtin_elementwise_min(__builtin_elementwise_max(zin,  F2(-10.f)), F2(10.f));
    floatx2 cp = __builtin_elementwise_min(__builtin_elementwise_max(cpin, F2(-10.f)), F2(10.f));
    floatx2 mz = z * F2(-LOG2E);
    floatx2 u  = {__builtin_amdgcn_exp2f(mz.x), __builtin_amdgcn_exp2f(mz.y)};
    floatx2 u2 = u * u;
    floatx2 mc = cp * F2(-2.f * LOG2E);
    floatx2 v  = {__builtin_amdgcn_exp2f(mc.x), __builtin_amdgcn_exp2f(mc.y)};
    floatx2 a1 = u + F2(1.f), a2 = u2 + F2(1.f), a3 = v + F2(1.f);
    floatx2 p12 = a1 * a2;
    floatx2 pr  = p12 * a3;
    floatx2 D   = {__builtin_amdgcn_rcpf(pr.x), __builtin_amdgcn_rcpf(pr.y)};
    floatx2 Da3 = D * a3;
    floatx2 g   = Da3 * a2;                 // sigmoid(z)
    floatx2 ir2 = Da3 * a1;                 // 1/(1+u2)
    floatx2 ir3 = D * p12;                  // 1/(1+v)
    floatx2 Cb  = ir2 - u2 * ir2;           // tanh(z)
    floatx2 Cs  = ir3 - v * ir3;            // tanh(cp)
    floatx2 Cst = cio - Cs * F2(wmv);       // c - Cs*(1-wt)
    floatx2 cn  = g * (Cst + Cb);
    floatx2 s   = Cb * Cb;                  // tanh(Cb) Taylor-13
    floatx2 P   = F2(0.003592028f);
    P = P * s + F2(-0.008863236f);
    P = P * s + F2(0.021869488f);
    P = P * s + F2(-0.053968254f);
    P = P * s + F2(0.133333333f);
    P = P * s + F2(-0.333333333f);
    P = P * s + F2(1.0f);
    floatx2 hn = g * (Cb * P);
    unsigned pk0 = cvtpk(hn.x, cn.x);       // lo=h, hi=c
    unsigned pk1 = cvtpk(hn.y, cn.y);
    Sst[woff + ih0]       = (unsigned short)pk0;
    Sst[woff + ih0 + 264] = (unsigned short)(pk0 >> 16);
    Sst[woff + ih1]       = (unsigned short)pk1;
    Sst[woff + ih1 + 264] = (unsigned short)(pk1 >> 16);
    cio = cn; gio = g; hio = hn;
  };

  floatx4 xa1, xa2;  // x-proj (+bi): [b2q parA, b2q parB, b2q+1 parA, b2q+1 parB]
  auto loadx = [&]() {
    short8 xf[4];
#pragma unroll
    for (int c = 0; c < 4; ++c)
      xf[c] = *(const short8*)&Sx[xro + raX + 32 * c];
    floatx4 x1 = {bi1, bi1, bi1, bi1};
    floatx4 x2 = {bi2, bi2, bi2, bi2};
#pragma unroll
    for (int c = 0; c < 4; ++c) {
      x1 = __builtin_amdgcn_mfma_f32_16x16x32_bf16(xf[c], wi[0][c], x1, 0, 0, 0);
      x2 = __builtin_amdgcn_mfma_f32_16x16x32_bf16(xf[c], wi[1][c], x2, 0, 0, 0);
    }
    xa1 = x1; xa2 = x2;
  };

  auto dostep = [&](int roff, int woff, int par, int wmoff) {
    short8 sf[8];
#pragma unroll
    for (int c = 0; c < 8; ++c)
      sf[c] = *(const short8*)&Sst[roff + raS + 32 * c];
    // 4 independent 4-deep chains: halves exposed MFMA latency
    floatx4 a1e = {bh1, bh1, bh1, bh1}, a1o = {0.f, 0.f, 0.f, 0.f};
    floatx4 a2e = {bh2, bh2, bh2, bh2}, a2o = {0.f, 0.f, 0.f, 0.f};
#pragma unroll
    for (int c = 0; c < 8; c += 2) {
      a1e = __builtin_amdgcn_mfma_f32_16x16x32_bf16(sf[c],     wh[0][c],     a1e, 0, 0, 0);
      a1o = __builtin_amdgcn_mfma_f32_16x16x32_bf16(sf[c + 1], wh[0][c + 1], a1o, 0, 0, 0);
      a2e = __builtin_amdgcn_mfma_f32_16x16x32_bf16(sf[c],     wh[1][c],     a2e, 0, 0, 0);
      a2o = __builtin_amdgcn_mfma_f32_16x16x32_bf16(sf[c + 1], wh[1][c + 1], a2o, 0, 0, 0);
    }
    floatx4 A1 = a1e + a1o;
    floatx4 A2 = a2e + a2o;
    floatx2 wm = *(const floatx2*)&WMt[wmoff];
    floatx2 z0  = {A1[0] + xa1[par],     A2[0] + xa2[par]};
    floatx2 cp0 = {A1[1],                A2[1]};
    floatx2 z1  = {A1[2] + xa1[2 + par], A2[2] + xa2[2 + par]};
    floatx2 cp1 = {A1[3],                A2[3]};
    proc2(z0, cp0, cP0, gP0, hP0, wm.x, wrA,       wrA + 16,  woff);
    proc2(z1, cp1, cP1, gP1, hP1, wm.y, wrA + 528, wrA + 544, woff);
    BAR();
  };

  for (int p = 0; p < 127; ++p) {
    floatx4 nv = *(const floatx4*)(xbase + (p + 1) * 256);  // next pair's x
    loadx();
    // step A (t = 2p): read buf0, write buf1
    dostep(0, 4224, 0, 16 * p + 2 * q);
    {  // finish staging next pair into the other x buffer
      uintx2 pk = {cvtpk(nv.x, nv.y), cvtpk(nv.z, nv.w)};
      *(uintx2*)&Sx[(xro ^ 2176) + xw] = pk;
    }
    // step B (t = 2p+1): read buf1, write buf0
    dostep(4224, 0, 1, 16 * p + 8 + 2 * q);
    xro ^= 2176;
  }

  // tail: t = 254 (step A of pair 127; staged at p=126)
  loadx();
  dostep(0, 4224, 0, 16 * 127 + 2 * q);

  // ---- epilogue: res = g_last @ Wh + bh; g-tile into buf0 ----
  Sst[wrA]       = f2bf(gP0.x);  Sst[wrA + 264] = 0;
  Sst[wrA + 528] = f2bf(gP1.x);  Sst[wrA + 792] = 0;
  Sst[wrA + 16]  = f2bf(gP0.y);  Sst[wrA + 280] = 0;
  Sst[wrA + 544] = f2bf(gP1.y);  Sst[wrA + 808] = 0;
  BAR();
  short8 gf[8];
#pragma unroll
  for (int c = 0; c < 8; ++c)
    gf[c] = *(const short8*)&Sst[raS + 32 * c];
  floatx4 r1 = {bh1, bh1, bh1, bh1};
  floatx4 r2 = {bh2, bh2, bh2, bh2};
#pragma unroll
  for (int c = 0; c < 8; ++c) {
    r1 = __builtin_amdgcn_mfma_f32_16x16x32_bf16(gf[c], wh[0][c], r1, 0, 0, 0);
    r2 = __builtin_amdgcn_mfma_f32_16x16x32_bf16(gf[c], wh[1][c], r2, 0, 0, 0);
  }

  const long P  = 2048L * 256;
  const long o0 = (long)(b0 + 2 * q) * 256;
  const long o1 = (long)(b0 + 2 * q + 1) * 256;
  out[o0 + col1]         = r1[0];
  out[o1 + col1]         = r1[2];
  out[o0 + col2]         = r2[0];
  out[o1 + col2]         = r2[2];
  out[P + o0 + col1]     = hP0.x;
  out[P + o1 + col1]     = hP1.x;
  out[P + o0 + col2]     = hP0.y;
  out[P + o1 + col2]     = hP1.y;
  out[2 * P + o0 + col1] = cP0.x;
  out[2 * P + o1 + col1] = cP1.x;
  out[2 * P + o0 + col2] = cP0.y;
  out[2 * P + o1 + col2] = cP1.y;
}

extern "C" void kernel_launch(void* const* d_in, const int* in_sizes, int n_in,
                              void* d_out, int out_size, void* d_ws, size_t ws_size,
                              hipStream_t stream) {
  const float* xin = (const float*)d_in[0];
  const float* tim = (const float*)d_in[1];
  const float* Wi  = (const float*)d_in[2];
  const float* bi  = (const float*)d_in[3];
  const float* Wh  = (const float*)d_in[4];
  const float* bh  = (const float*)d_in[5];
  tlstm_kernel<<<dim3(256), dim3(512), 0, stream>>>(xin, tim, Wi, bi, Wh, bh, (float*)d_out);
}